// Round 5
// baseline (244.132 us; speedup 1.0000x reference)
//
#include <hip/hip_runtime.h>
#include <math.h>

// Problem constants (B, CIN, COUT, K, S, P, D) = (4,128,128,3,1,1,1), H=W=96
#define HH 96
#define WW 96
#define HW (96*96)
#define CIN_ 128
#define COUT_ 128
#define OUT_ELEMS (4*128*96*96)
#define TPX 48            // pixels per conv block: 768 blocks = exactly 3/CU
#define NBLK 768

// ws layout (bytes)
#define XT_OFF   0u           // x_t bf16 [4][9216][128] = 9,437,184 B
#define WBF_OFF  9437184u     // wbf bf16 [128][1152] (q=kc*128+c) = 294,912 B
#define WOMB_OFF 9732096u     // womb bf16 [32][1152] (rows>=27 zero) = 73,728 B
#define BAR_OFF  9805824u     // grid-barrier counter (memset to 0 each launch)

typedef __attribute__((ext_vector_type(8))) short short8v;
typedef __attribute__((ext_vector_type(4))) float float4v;

__device__ __forceinline__ unsigned short f2bf(float f) {
    unsigned u = __builtin_bit_cast(unsigned, f);
    u += 0x7FFFu + ((u >> 16) & 1u);   // RNE (inputs finite)
    return (unsigned short)(u >> 16);
}
__device__ __forceinline__ unsigned rneu(float f) {
    unsigned u = __builtin_bit_cast(unsigned, f);
    return u + 0x7FFFu + ((u >> 16) & 1u);
}
// pack bf16(hi)<<16 | bf16(lo) in one v_perm_b32 (bit-identical to f2bf pair)
__device__ __forceinline__ unsigned pkbf(float hi, float lo) {
    return __builtin_amdgcn_perm(rneu(hi), rneu(lo), 0x07060302u);
}
__device__ __forceinline__ float bflo(unsigned u) {
    return __builtin_bit_cast(float, u << 16);
}
__device__ __forceinline__ float bfhi(unsigned u) {
    return __builtin_bit_cast(float, u & 0xffff0000u);
}

// Raw barrier: drain LDS ops only; global loads stay in flight (T4 pattern).
#define BLOCK_SYNC() do {                                   \
    __builtin_amdgcn_sched_barrier(0);                      \
    asm volatile("s_waitcnt lgkmcnt(0)" ::: "memory");      \
    __builtin_amdgcn_s_barrier();                           \
    __builtin_amdgcn_sched_barrier(0);                      \
} while (0)

// ---------------------------------------------------------------------------
// ONE persistent kernel, grid 768 x 512 (3 blocks/CU co-resident by
// construction: 6144 waves <= 8192 slots, 3x38.4KB <= 160KB LDS,
// launch_bounds(512,6) caps VGPR<=84).
// Stage A: blocks [0,576) transpose x -> x_t bf16 (XCD-aligned slices);
//          blocks [576,768) convert weights to bf16.
// Manual device-scope grid barrier (counter memset'd to 0 per launch).
// Stage B: per 48-px tile (XCD-aligned, same slice stage A produced on this
//          XCD): om GEMM -> sampling prep -> pipelined gather + MFMA GEMM.
//          In-loop barriers are RAW (lgkmcnt-only drain) so the 16 prefetch
//          loads per wave stay outstanding across the barrier + MFMA phase.
// LDS (38400 B): sprep 13824 | btile0 12288 | btile1 12288 (som aliases
// btile0; stage-A transpose tile aliases the same pool).
// ---------------------------------------------------------------------------
__global__ __launch_bounds__(512, 6) void fused_all(
    const float* __restrict__ x, const float* __restrict__ weight,
    const float* __restrict__ bias, const float* __restrict__ wom,
    float* __restrict__ out, float* __restrict__ off_out,
    unsigned short* __restrict__ xt, unsigned short* __restrict__ wbf,
    unsigned short* __restrict__ womb, unsigned int* __restrict__ bar)
{
    __shared__ int smem[9600];           // 38400 B
    const int t = threadIdx.x;
    const int f = blockIdx.x;

    // ================= stage A =================
    if (f < 576) {
        float (*tile)[130] = (float(*)[130])smem;    // 33280 B < 38400
        const int g  = (f & 7) * 72 + (f >> 3);      // bijective [0,576)
        const int b  = g / 144;
        const int p0 = (g - b * 144) * 64;
#pragma unroll
        for (int j = 0; j < 4; j++) {                // read: float4 per thread
            const int i  = j * 512 + t;
            const int c  = i >> 4;
            const int p4 = (i & 15) * 4;
            const float4 v = *(const float4*)(x + ((size_t)(b * CIN_ + c) * HW + p0 + p4));
            tile[p4 + 0][c] = v.x; tile[p4 + 1][c] = v.y;
            tile[p4 + 2][c] = v.z; tile[p4 + 3][c] = v.w;
        }
        __syncthreads();
#pragma unroll
        for (int j = 0; j < 4; j++) {                // write: 4 c per thread (8 B)
            const int i   = j * 512 + t;
            const int pxl = i >> 5;
            const int c4  = (i & 31) * 4;
            uint2 v;
            v.x = pkbf(tile[pxl][c4 + 1], tile[pxl][c4 + 0]);
            v.y = pkbf(tile[pxl][c4 + 3], tile[pxl][c4 + 2]);
            *(uint2*)(xt + ((size_t)(b * HW + p0 + pxl) * CIN_ + c4)) = v;
        }
    } else {
        const int base = (f - 576) * 1024;
#pragma unroll
        for (int k = 0; k < 2; k++) {
            const int i = base + k * 512 + t;
            if (i < COUT_ * 1152) {
                const int oc = i / 1152, r = i - oc * 1152;
                const int kc = r >> 7, c = r & 127;
                wbf[i] = f2bf(weight[(size_t)oc * 1152 + c * 9 + kc]);
            } else {
                const int i2 = i - COUT_ * 1152;
                if (i2 < 32 * 1152) {
                    const int row = i2 / 1152, r = i2 - row * 1152;
                    const int kc = r >> 7, c = r & 127;
                    womb[i2] = (row < 27) ? f2bf(wom[(size_t)row * 1152 + c * 9 + kc]) : 0;
                }
            }
        }
    }

    // ============ device-wide barrier (all 768 blocks co-resident) =========
    __syncthreads();                      // per-wave vmcnt(0) drain included
    if (t == 0) {
        __threadfence();                  // release: L2 writeback (agent)
        __hip_atomic_fetch_add(bar, 1u, __ATOMIC_ACQ_REL, __HIP_MEMORY_SCOPE_AGENT);
        while (__hip_atomic_load(bar, __ATOMIC_RELAXED, __HIP_MEMORY_SCOPE_AGENT) < NBLK)
            __builtin_amdgcn_s_sleep(2);
        __threadfence();                  // acquire: invalidate stale lines
    }
    __syncthreads();

    // ================= stage B =================
    int*   sprep  = smem;                 // [432*8]
    int*   btile0 = smem + 3456;          // [48*64]
    int*   btile1 = smem + 6528;          // [48*64]
    float* som    = (float*)btile0;       // [27][48] (alias)

    const int wave = __builtin_amdgcn_readfirstlane(t >> 6);
    const int lane = t & 63;
    const int quad = lane >> 4;
    const int m    = lane & 15;
    const int l32  = lane & 31;
    const int half = lane >> 5;

    const int c  = (f & 7) * 96 + (f >> 3);          // bijective [0,768)
    const int b  = c / 192;
    const int p0 = (c - b * 192) * TPX;

    const unsigned short* xtb = xt + (size_t)b * HW * CIN_;

    // ---- phase 0: offset/mask conv for this block's own pixels ------------
    if (wave < 6) {
        const int pxg = wave >> 1;
        const int mt  = wave & 1;
        const int pgl = pxg * 16 + m;
        const int pg  = p0 + pgl;
        const int h   = pg / 96;
        const int w   = pg - h * 96;

        float4v acc2;
#pragma unroll
        for (int r = 0; r < 4; r++) acc2[r] = 0.f;
        const short8v zerov = (short8v)0;

#pragma unroll
        for (int kc = 0; kc < 9; kc++) {
            const int ki = kc / 3, kj = kc - 3 * (kc / 3);
            const int y  = h + ki - 1, xx = w + kj - 1;
            const bool valid = ((unsigned)y < 96u) && ((unsigned)xx < 96u);
            const unsigned short* brow = xtb + (size_t)(y * 96 + xx) * CIN_ + quad * 8;
            const short* abase = (const short*)womb + (size_t)(mt * 16 + m) * 1152 + kc * 128 + quad * 8;
#pragma unroll
            for (int kst = 0; kst < 4; kst++) {
                const short8v bfv = valid ? *(const short8v*)(brow + kst * 32) : zerov;
                const short8v av  = *(const short8v*)(abase + kst * 32);
                acc2 = __builtin_amdgcn_mfma_f32_16x16x32_bf16(av, bfv, acc2, 0, 0, 0);
            }
        }
#pragma unroll
        for (int r = 0; r < 4; r++) {
            const int oc = mt * 16 + quad * 4 + r;
            if (oc < 27) som[oc * TPX + pgl] = acc2[r];
            if (oc < 18) off_out[(size_t)(b * 18 + oc) * HW + pg] = acc2[r];
        }
    }
    __syncthreads();

    // ---- phase 1: sampling prep (reads som, writes sprep) -----------------
    if (t < 432) {
        const int kc  = t / 48;
        const int pxl = t - kc * 48;
        const int pg  = p0 + pxl;
        const int h   = pg / 96;
        const int w   = pg - h * 96;
        const int ki  = kc / 3, kj = kc - 3 * (kc / 3);

        const float o1 = som[kc * TPX + pxl];
        const float o2 = som[(9 + kc) * TPX + pxl];
        const float mr = som[(18 + kc) * TPX + pxl];
        const float mk = 2.f / (1.f + __expf(-mr));   // sigmoid * MASK_SCALE

        const float py = (float)(h - 1 + ki) + o1;
        const float px = (float)(w - 1 + kj) + o2;
        const float y0f = floorf(py), x0f = floorf(px);
        const float ly = py - y0f,    lx = px - x0f;
        const int y0 = (int)y0f, x0 = (int)x0f;
        const int y1 = y0 + 1,   x1 = x0 + 1;

        const float w00 = (1.f - ly) * (1.f - lx), w01 = (1.f - ly) * lx;
        const float w10 = ly * (1.f - lx),         w11 = ly * lx;

        const int yc0 = min(max(y0, 0), HH - 1), yc1 = min(max(y1, 0), HH - 1);
        const int xc0 = min(max(x0, 0), WW - 1), xc1 = min(max(x1, 0), WW - 1);
        const bool vy0 = (y0 >= 0) && (y0 < HH), vy1 = (y1 >= 0) && (y1 < HH);
        const bool vx0 = (x0 >= 0) && (x0 < WW), vx1 = (x1 >= 0) && (x1 < WW);

        sprep[t * 8 + 0] = yc0 * 96 + xc0;
        sprep[t * 8 + 1] = yc0 * 96 + xc1;
        sprep[t * 8 + 2] = yc1 * 96 + xc0;
        sprep[t * 8 + 3] = yc1 * 96 + xc1;
        sprep[t * 8 + 4] = __builtin_bit_cast(int, (vy0 && vx0) ? mk * w00 : 0.f);
        sprep[t * 8 + 5] = __builtin_bit_cast(int, (vy0 && vx1) ? mk * w01 : 0.f);
        sprep[t * 8 + 6] = __builtin_bit_cast(int, (vy1 && vx0) ? mk * w10 : 0.f);
        sprep[t * 8 + 7] = __builtin_bit_cast(int, (vy1 && vx1) ? mk * w11 : 0.f);
    }
    __syncthreads();

    // ---- phase 2: pipelined gather + main GEMM (raw in-loop barriers) -----
    uint2 gbuf[3][4];

#define ISSUE(SL, KCV, ITV) do {                                              \
    const int pxl_ = wave * 6 + (ITV) * 2 + half;                             \
    const int4 id4_ = *(const int4*)&sprep[((KCV) * 48 + pxl_) * 8];          \
    const unsigned co_ = (unsigned)l32 << 3;                                  \
    gbuf[SL][0] = *(const uint2*)((const char*)xtb + (((unsigned)id4_.x << 8) | co_)); \
    gbuf[SL][1] = *(const uint2*)((const char*)xtb + (((unsigned)id4_.y << 8) | co_)); \
    gbuf[SL][2] = *(const uint2*)((const char*)xtb + (((unsigned)id4_.z << 8) | co_)); \
    gbuf[SL][3] = *(const uint2*)((const char*)xtb + (((unsigned)id4_.w << 8) | co_)); \
} while (0)

#define COMBINE(SL, IV) do {                                                  \
    const int pxl_ = wave * 6 + (IV) * 2 + half;                              \
    const float4 w4_ = *(const float4*)&sprep[(kc * 48 + pxl_) * 8 + 4];      \
    const uint2 u0 = gbuf[SL][0], u1 = gbuf[SL][1];                           \
    const uint2 u2 = gbuf[SL][2], u3 = gbuf[SL][3];                           \
    const float v0 = w4_.x*bflo(u0.x) + w4_.y*bflo(u1.x) + w4_.z*bflo(u2.x) + w4_.w*bflo(u3.x); \
    const float v1 = w4_.x*bfhi(u0.x) + w4_.y*bfhi(u1.x) + w4_.z*bfhi(u2.x) + w4_.w*bfhi(u3.x); \
    const float v2 = w4_.x*bflo(u0.y) + w4_.y*bflo(u1.y) + w4_.z*bflo(u2.y) + w4_.w*bflo(u3.y); \
    const float v3 = w4_.x*bfhi(u0.y) + w4_.y*bfhi(u1.y) + w4_.z*bfhi(u2.y) + w4_.w*bfhi(u3.y); \
    uint2 o_;                                                                 \
    o_.x = pkbf(v1, v0);                                                      \
    o_.y = pkbf(v3, v2);                                                      \
    *(uint2*)&bt[pxl_ * 64 + (((l32 >> 1) ^ (pxl_ & 7)) << 2) + ((l32 & 1) << 1)] = o_; \
} while (0)

    float4v acc[3];
#pragma unroll
    for (int j = 0; j < 3; j++)
#pragma unroll
        for (int r = 0; r < 4; r++) acc[j][r] = 0.f;

    // prologue: all three iter-loads of kc=0 in flight
    ISSUE(0, 0, 0);
    ISSUE(1, 0, 1);
    ISSUE(2, 0, 2);

    for (int kc = 0; kc < 9; kc++) {
        int* bt = (kc & 1) ? btile1 : btile0;

        // A-fragments for this kc — issued at phase top, used after barrier
        const short* abase = (const short*)wbf + (size_t)(wave * 16 + m) * 1152 + kc * 128 + quad * 8;
        short8v af[4];
#pragma unroll
        for (int kst = 0; kst < 4; kst++)
            af[kst] = *(const short8v*)(abase + kst * 32);

        // consume slot, immediately reissue it one phase ahead
        COMBINE(0, 0);
        if (kc < 8) ISSUE(0, kc + 1, 0);
        COMBINE(1, 1);
        if (kc < 8) ISSUE(1, kc + 1, 1);
        COMBINE(2, 2);
        if (kc < 8) ISSUE(2, kc + 1, 2);

        BLOCK_SYNC();   // drains LDS writes only; gather/af loads stay in flight

        // MFMA: wave = 16-oc slice; 4 kst x 3 nt; swizzle-matched reads
#pragma unroll
        for (int kst = 0; kst < 4; kst++) {
#pragma unroll
            for (int nt = 0; nt < 3; nt++) {
                const int pxl = nt * 16 + m;
                const short8v bfv = *(const short8v*)((const short*)bt
                    + 2 * (pxl * 64 + (((kst * 4 + quad) ^ (m & 7)) << 2)));
                acc[nt] = __builtin_amdgcn_mfma_f32_16x16x32_bf16(af[kst], bfv, acc[nt], 0, 0, 0);
            }
        }
        // no trailing barrier: next kc writes the other buffer; this kc's
        // ds_reads drain at the next BLOCK_SYNC's lgkmcnt(0) before any wave
        // can reach the kc+2 writes to this buffer.
    }
#undef ISSUE
#undef COMBINE

    // ---- epilogue ---------------------------------------------------------
#pragma unroll
    for (int r = 0; r < 4; r++) {
        const int oc = wave * 16 + quad * 4 + r;
        const float bv = bias[oc];
#pragma unroll
        for (int nt = 0; nt < 3; nt++)
            out[(size_t)(b * COUT_ + oc) * HW + p0 + nt * 16 + m] = acc[nt][r] + bv;
    }
}

extern "C" void kernel_launch(void* const* d_in, const int* in_sizes, int n_in,
                              void* d_out, int out_size, void* d_ws, size_t ws_size,
                              hipStream_t stream) {
    const float* x      = (const float*)d_in[0];
    const float* weight = (const float*)d_in[1];
    const float* bias   = (const float*)d_in[2];
    const float* wom    = (const float*)d_in[3];

    float* out     = (float*)d_out;
    float* off_out = out + OUT_ELEMS;

    unsigned short* xtb  = (unsigned short*)((char*)d_ws + XT_OFF);
    unsigned short* wbf  = (unsigned short*)((char*)d_ws + WBF_OFF);
    unsigned short* womb = (unsigned short*)((char*)d_ws + WOMB_OFF);
    unsigned int*   bar  = (unsigned int*)((char*)d_ws + BAR_OFF);

    hipMemsetAsync((void*)bar, 0, 64, stream);
    fused_all<<<dim3(NBLK), 512, 0, stream>>>(x, weight, bias, wom, out, off_out,
                                              xtb, wbf, womb, bar);
}

// Round 6
// 161.431 us; speedup vs baseline: 1.5123x; 1.5123x over previous
//
#include <hip/hip_runtime.h>
#include <math.h>

// Problem constants (B, CIN, COUT, K, S, P, D) = (4,128,128,3,1,1,1), H=W=96
#define HH 96
#define WW 96
#define HW (96*96)
#define CIN_ 128
#define COUT_ 128
#define OUT_ELEMS (4*128*96*96)
#define TPX 48            // pixels per conv block: 768 blocks = exactly 3/CU

// ws layout (bytes)
#define XT_OFF   0u           // x_t bf16 [4][9216][128] = 9,437,184 B
#define WBF_OFF  9437184u     // wbf bf16 [128][1152] (q=kc*128+c) = 294,912 B
#define WOMB_OFF 9732096u     // womb bf16 [32][1152] (rows>=27 zero) = 73,728 B

typedef __attribute__((ext_vector_type(8))) short short8v;
typedef __attribute__((ext_vector_type(4))) float float4v;

__device__ __forceinline__ unsigned short f2bf(float f) {
    unsigned u = __builtin_bit_cast(unsigned, f);
    u += 0x7FFFu + ((u >> 16) & 1u);   // RNE (inputs finite)
    return (unsigned short)(u >> 16);
}
__device__ __forceinline__ unsigned rneu(float f) {
    unsigned u = __builtin_bit_cast(unsigned, f);
    return u + 0x7FFFu + ((u >> 16) & 1u);
}
// pack bf16(hi)<<16 | bf16(lo) in one v_perm_b32 (bit-identical to f2bf pair)
__device__ __forceinline__ unsigned pkbf(float hi, float lo) {
    return __builtin_amdgcn_perm(rneu(hi), rneu(lo), 0x07060302u);
}
__device__ __forceinline__ float bflo(unsigned u) {
    return __builtin_bit_cast(float, u << 16);
}
__device__ __forceinline__ float bfhi(unsigned u) {
    return __builtin_bit_cast(float, u & 0xffff0000u);
}

// Raw block barrier: drains LDS ops only (lgkmcnt).  Unlike __syncthreads(),
// pending GLOBAL loads (gather/af prefetch) stay in flight across it — this
// is the whole point (T4: __syncthreads emits s_waitcnt vmcnt(0) and kills
// MLP once per kc).  sched_barrier(0) on both sides pins code motion
// (rule #18: register-only MFMA can hoist past inline-asm waits).
#define BLOCK_SYNC() do {                                   \
    __builtin_amdgcn_sched_barrier(0);                      \
    asm volatile("s_waitcnt lgkmcnt(0)" ::: "memory");      \
    __builtin_amdgcn_s_barrier();                           \
    __builtin_amdgcn_sched_barrier(0);                      \
} while (0)

// ---------------------------------------------------------------------------
// Merged prep: blocks [0,576) transpose x -> x_t bf16 (XCD-aligned tiles:
// XCD k = f&7 produces pixel slice [k*4608,(k+1)*4608) of the px space);
// blocks [576,1296) convert weights to bf16 (q reordered to kc*128+c).
// ---------------------------------------------------------------------------
__global__ __launch_bounds__(256) void pre_kernel(
    const float* __restrict__ x, const float* __restrict__ w,
    const float* __restrict__ wom, unsigned short* __restrict__ xt,
    unsigned short* __restrict__ wbf, unsigned short* __restrict__ womb)
{
    __shared__ float tile[64][130];
    const int t = threadIdx.x;
    const int f = blockIdx.x;

    if (f < 576) {
        const int g  = (f & 7) * 72 + (f >> 3);      // bijective [0,576)
        const int b  = g / 144;
        const int p0 = (g - b * 144) * 64;
#pragma unroll
        for (int j = 0; j < 8; j++) {               // read: 4 px per thread (float4)
            const int i  = j * 256 + t;
            const int c  = i >> 4;
            const int p4 = (i & 15) * 4;
            const float4 v = *(const float4*)(x + ((size_t)(b * CIN_ + c) * HW + p0 + p4));
            tile[p4 + 0][c] = v.x; tile[p4 + 1][c] = v.y;
            tile[p4 + 2][c] = v.z; tile[p4 + 3][c] = v.w;
        }
        __syncthreads();
#pragma unroll
        for (int j = 0; j < 8; j++) {               // write: 4 c per thread (8 B bf16)
            const int i   = j * 256 + t;
            const int pxl = i >> 5;
            const int c4  = (i & 31) * 4;
            uint2 v;
            v.x = pkbf(tile[pxl][c4 + 1], tile[pxl][c4 + 0]);
            v.y = pkbf(tile[pxl][c4 + 3], tile[pxl][c4 + 2]);
            *(uint2*)(xt + ((size_t)(b * HW + p0 + pxl) * CIN_ + c4)) = v;
        }
    } else {
        const int i = (f - 576) * 256 + t;
        if (i < COUT_ * 1152) {
            const int oc = i / 1152, r = i - oc * 1152;
            const int kc = r >> 7, c = r & 127;
            wbf[i] = f2bf(w[(size_t)oc * 1152 + c * 9 + kc]);
        } else {
            const int i2 = i - COUT_ * 1152;
            if (i2 < 32 * 1152) {
                const int row = i2 / 1152, r = i2 - row * 1152;
                const int kc = r >> 7, c = r & 127;
                womb[i2] = (row < 27) ? f2bf(wom[(size_t)row * 1152 + c * 9 + kc]) : 0;
            }
        }
    }
}

// ---------------------------------------------------------------------------
// Fused conv kernel.  Grid 768 (1D, XCD-aligned: XCD k = f&7 consumes the
// same px slice stage A produced there), 512 thr, 48 px / block.
//   phase 0: waves 0..5 compute om = womb @ x_t for this block's 48 px;
//            results -> som (LDS), rows<18 also -> off_out (global).
//   phase 1: 432 threads build sprep (bilinear corners + mask*weights).
//   phase 2: per kc, one-phase-deep pipeline:
//              af loads (kc)                         } issued at phase top,
//              COMBINE(s,kc); ISSUE(s,kc+1)  s=0..2  } consumed next phase
//              BLOCK_SYNC (lgkmcnt-only!); MFMA(kc)
//            The raw barrier keeps the 16 prefetched global loads per wave
//            IN FLIGHT across the barrier and under the MFMA phase — the
//            vmcnt(0) drain of __syncthreads() was the structural stall.
// LDS (38400 B): sprep 13824 | btile0 12288 | btile1 12288 (som aliases
// btile0, consumed before kc=0's gather writes it).
// ---------------------------------------------------------------------------
__global__ __launch_bounds__(512, 6) void dconv_fused(
    const unsigned short* __restrict__ xt, const unsigned short* __restrict__ wbf,
    const unsigned short* __restrict__ womb, const float* __restrict__ bias,
    float* __restrict__ out, float* __restrict__ off_out)
{
    __shared__ int smem[9600];           // 38400 B
    int*   sprep  = smem;                 // [432*8]
    int*   btile0 = smem + 3456;          // [48*64]
    int*   btile1 = smem + 6528;          // [48*64]
    float* som    = (float*)btile0;       // [27][48] (alias)

    const int t    = threadIdx.x;
    const int wave = __builtin_amdgcn_readfirstlane(t >> 6);
    const int lane = t & 63;
    const int quad = lane >> 4;
    const int m    = lane & 15;
    const int l32  = lane & 31;
    const int half = lane >> 5;

    const int f  = blockIdx.x;
    const int c  = (f & 7) * 96 + (f >> 3);          // bijective [0,768)
    const int b  = c / 192;
    const int p0 = (c - b * 192) * TPX;

    const unsigned short* xtb = xt + (size_t)b * HW * CIN_;

    // ---- phase 0: offset/mask conv for this block's own pixels ------------
    if (wave < 6) {
        const int pxg = wave >> 1;
        const int mt  = wave & 1;
        const int pgl = pxg * 16 + m;
        const int pg  = p0 + pgl;
        const int h   = pg / 96;
        const int w   = pg - h * 96;

        float4v acc2;
#pragma unroll
        for (int r = 0; r < 4; r++) acc2[r] = 0.f;
        const short8v zerov = (short8v)0;

#pragma unroll
        for (int kc = 0; kc < 9; kc++) {
            const int ki = kc / 3, kj = kc - 3 * (kc / 3);
            const int y  = h + ki - 1, xx = w + kj - 1;
            const bool valid = ((unsigned)y < 96u) && ((unsigned)xx < 96u);
            const unsigned short* brow = xtb + (size_t)(y * 96 + xx) * CIN_ + quad * 8;
            const short* abase = (const short*)womb + (size_t)(mt * 16 + m) * 1152 + kc * 128 + quad * 8;
#pragma unroll
            for (int kst = 0; kst < 4; kst++) {
                const short8v bfv = valid ? *(const short8v*)(brow + kst * 32) : zerov;
                const short8v av  = *(const short8v*)(abase + kst * 32);
                acc2 = __builtin_amdgcn_mfma_f32_16x16x32_bf16(av, bfv, acc2, 0, 0, 0);
            }
        }
#pragma unroll
        for (int r = 0; r < 4; r++) {
            const int oc = mt * 16 + quad * 4 + r;
            if (oc < 27) som[oc * TPX + pgl] = acc2[r];
            if (oc < 18) off_out[(size_t)(b * 18 + oc) * HW + pg] = acc2[r];
        }
    }
    __syncthreads();

    // ---- phase 1: sampling prep (reads som, writes sprep) -----------------
    if (t < 432) {
        const int kc  = t / 48;
        const int pxl = t - kc * 48;
        const int pg  = p0 + pxl;
        const int h   = pg / 96;
        const int w   = pg - h * 96;
        const int ki  = kc / 3, kj = kc - 3 * (kc / 3);

        const float o1 = som[kc * TPX + pxl];
        const float o2 = som[(9 + kc) * TPX + pxl];
        const float mr = som[(18 + kc) * TPX + pxl];
        const float mk = 2.f / (1.f + __expf(-mr));   // sigmoid * MASK_SCALE

        const float py = (float)(h - 1 + ki) + o1;
        const float px = (float)(w - 1 + kj) + o2;
        const float y0f = floorf(py), x0f = floorf(px);
        const float ly = py - y0f,    lx = px - x0f;
        const int y0 = (int)y0f, x0 = (int)x0f;
        const int y1 = y0 + 1,   x1 = x0 + 1;

        const float w00 = (1.f - ly) * (1.f - lx), w01 = (1.f - ly) * lx;
        const float w10 = ly * (1.f - lx),         w11 = ly * lx;

        const int yc0 = min(max(y0, 0), HH - 1), yc1 = min(max(y1, 0), HH - 1);
        const int xc0 = min(max(x0, 0), WW - 1), xc1 = min(max(x1, 0), WW - 1);
        const bool vy0 = (y0 >= 0) && (y0 < HH), vy1 = (y1 >= 0) && (y1 < HH);
        const bool vx0 = (x0 >= 0) && (x0 < WW), vx1 = (x1 >= 0) && (x1 < WW);

        sprep[t * 8 + 0] = yc0 * 96 + xc0;
        sprep[t * 8 + 1] = yc0 * 96 + xc1;
        sprep[t * 8 + 2] = yc1 * 96 + xc0;
        sprep[t * 8 + 3] = yc1 * 96 + xc1;
        sprep[t * 8 + 4] = __builtin_bit_cast(int, (vy0 && vx0) ? mk * w00 : 0.f);
        sprep[t * 8 + 5] = __builtin_bit_cast(int, (vy0 && vx1) ? mk * w01 : 0.f);
        sprep[t * 8 + 6] = __builtin_bit_cast(int, (vy1 && vx0) ? mk * w10 : 0.f);
        sprep[t * 8 + 7] = __builtin_bit_cast(int, (vy1 && vx1) ? mk * w11 : 0.f);
    }
    __syncthreads();

    // ---- phase 2: pipelined gather + main GEMM (raw in-loop barriers) -----
    uint2 gbuf[3][4];

#define ISSUE(SL, KCV, ITV) do {                                              \
    const int pxl_ = wave * 6 + (ITV) * 2 + half;                             \
    const int4 id4_ = *(const int4*)&sprep[((KCV) * 48 + pxl_) * 8];          \
    const unsigned co_ = (unsigned)l32 << 3;                                  \
    gbuf[SL][0] = *(const uint2*)((const char*)xtb + (((unsigned)id4_.x << 8) | co_)); \
    gbuf[SL][1] = *(const uint2*)((const char*)xtb + (((unsigned)id4_.y << 8) | co_)); \
    gbuf[SL][2] = *(const uint2*)((const char*)xtb + (((unsigned)id4_.z << 8) | co_)); \
    gbuf[SL][3] = *(const uint2*)((const char*)xtb + (((unsigned)id4_.w << 8) | co_)); \
} while (0)

#define COMBINE(SL, IV) do {                                                  \
    const int pxl_ = wave * 6 + (IV) * 2 + half;                              \
    const float4 w4_ = *(const float4*)&sprep[(kc * 48 + pxl_) * 8 + 4];      \
    const uint2 u0 = gbuf[SL][0], u1 = gbuf[SL][1];                           \
    const uint2 u2 = gbuf[SL][2], u3 = gbuf[SL][3];                           \
    const float v0 = w4_.x*bflo(u0.x) + w4_.y*bflo(u1.x) + w4_.z*bflo(u2.x) + w4_.w*bflo(u3.x); \
    const float v1 = w4_.x*bfhi(u0.x) + w4_.y*bfhi(u1.x) + w4_.z*bfhi(u2.x) + w4_.w*bfhi(u3.x); \
    const float v2 = w4_.x*bflo(u0.y) + w4_.y*bflo(u1.y) + w4_.z*bflo(u2.y) + w4_.w*bflo(u3.y); \
    const float v3 = w4_.x*bfhi(u0.y) + w4_.y*bfhi(u1.y) + w4_.z*bfhi(u2.y) + w4_.w*bfhi(u3.y); \
    uint2 o_;                                                                 \
    o_.x = pkbf(v1, v0);                                                      \
    o_.y = pkbf(v3, v2);                                                      \
    *(uint2*)&bt[pxl_ * 64 + (((l32 >> 1) ^ (pxl_ & 7)) << 2) + ((l32 & 1) << 1)] = o_; \
} while (0)

    float4v acc[3];
#pragma unroll
    for (int j = 0; j < 3; j++)
#pragma unroll
        for (int r = 0; r < 4; r++) acc[j][r] = 0.f;

    // prologue: all three iter-loads of kc=0 in flight
    ISSUE(0, 0, 0);
    ISSUE(1, 0, 1);
    ISSUE(2, 0, 2);

    for (int kc = 0; kc < 9; kc++) {
        int* bt = (kc & 1) ? btile1 : btile0;

        // A-fragments for this kc — issued at phase top, used after barrier
        const short* abase = (const short*)wbf + (size_t)(wave * 16 + m) * 1152 + kc * 128 + quad * 8;
        short8v af[4];
#pragma unroll
        for (int kst = 0; kst < 4; kst++)
            af[kst] = *(const short8v*)(abase + kst * 32);

        // consume slot, immediately reissue it one phase ahead
        COMBINE(0, 0);
        if (kc < 8) ISSUE(0, kc + 1, 0);
        COMBINE(1, 1);
        if (kc < 8) ISSUE(1, kc + 1, 1);
        COMBINE(2, 2);
        if (kc < 8) ISSUE(2, kc + 1, 2);

        BLOCK_SYNC();   // drains LDS writes only; gather/af loads stay in flight

        // MFMA: wave = 16-oc slice; 4 kst x 3 nt; swizzle-matched reads
#pragma unroll
        for (int kst = 0; kst < 4; kst++) {
#pragma unroll
            for (int nt = 0; nt < 3; nt++) {
                const int pxl = nt * 16 + m;
                const short8v bfv = *(const short8v*)((const short*)bt
                    + 2 * (pxl * 64 + (((kst * 4 + quad) ^ (m & 7)) << 2)));
                acc[nt] = __builtin_amdgcn_mfma_f32_16x16x32_bf16(af[kst], bfv, acc[nt], 0, 0, 0);
            }
        }
        // no trailing barrier: next kc writes the other buffer; this kc's
        // ds_reads drain at the next BLOCK_SYNC's lgkmcnt(0) before any wave
        // can reach the kc+2 writes to this buffer.
    }
#undef ISSUE
#undef COMBINE

    // ---- epilogue ---------------------------------------------------------
#pragma unroll
    for (int r = 0; r < 4; r++) {
        const int oc = wave * 16 + quad * 4 + r;
        const float bv = bias[oc];
#pragma unroll
        for (int nt = 0; nt < 3; nt++)
            out[(size_t)(b * COUT_ + oc) * HW + p0 + nt * 16 + m] = acc[nt][r] + bv;
    }
}

extern "C" void kernel_launch(void* const* d_in, const int* in_sizes, int n_in,
                              void* d_out, int out_size, void* d_ws, size_t ws_size,
                              hipStream_t stream) {
    const float* x      = (const float*)d_in[0];
    const float* weight = (const float*)d_in[1];
    const float* bias   = (const float*)d_in[2];
    const float* wom    = (const float*)d_in[3];

    float* out     = (float*)d_out;
    float* off_out = out + OUT_ELEMS;

    unsigned short* xtb  = (unsigned short*)((char*)d_ws + XT_OFF);
    unsigned short* wbf  = (unsigned short*)((char*)d_ws + WBF_OFF);
    unsigned short* womb = (unsigned short*)((char*)d_ws + WOMB_OFF);

    pre_kernel <<<dim3(1296), 256, 0, stream>>>(x, weight, wom, xtb, wbf, womb);
    dconv_fused<<<dim3(768),  512, 0, stream>>>(xtb, wbf, womb, bias, out, off_out);
}

// Round 7
// 145.858 us; speedup vs baseline: 1.6738x; 1.1068x over previous
//
#include <hip/hip_runtime.h>
#include <math.h>

// Problem constants (B, CIN, COUT, K, S, P, D) = (4,128,128,3,1,1,1), H=W=96
#define HH 96
#define WW 96
#define HW (96*96)
#define CIN_ 128
#define COUT_ 128
#define OUT_ELEMS (4*128*96*96)
#define TPX 48            // pixels per conv block: 768 blocks = exactly 3/CU

// ws layout (bytes)
#define XT_OFF   0u           // x_t bf16 [4][9216][128] = 9,437,184 B
#define WBF_OFF  9437184u     // wbf bf16 [128][1152] (q=kc*128+c) = 294,912 B
#define WOMB_OFF 9732096u     // womb bf16 [32][1152] (rows>=27 zero) = 73,728 B

typedef __attribute__((ext_vector_type(8))) short short8v;
typedef __attribute__((ext_vector_type(4))) float float4v;

__device__ __forceinline__ unsigned short f2bf(float f) {
    unsigned u = __builtin_bit_cast(unsigned, f);
    u += 0x7FFFu + ((u >> 16) & 1u);   // RNE (inputs finite)
    return (unsigned short)(u >> 16);
}
__device__ __forceinline__ unsigned rneu(float f) {
    unsigned u = __builtin_bit_cast(unsigned, f);
    return u + 0x7FFFu + ((u >> 16) & 1u);
}
// pack bf16(hi)<<16 | bf16(lo) in one v_perm_b32 (bit-identical to f2bf pair)
__device__ __forceinline__ unsigned pkbf(float hi, float lo) {
    return __builtin_amdgcn_perm(rneu(hi), rneu(lo), 0x07060302u);
}
__device__ __forceinline__ float bflo(unsigned u) {
    return __builtin_bit_cast(float, u << 16);
}
__device__ __forceinline__ float bfhi(unsigned u) {
    return __builtin_bit_cast(float, u & 0xffff0000u);
}

// Raw block barrier: drains LDS ops only (lgkmcnt); pending global loads
// stay in flight.  Proven-passing (round 6).  sched_barrier(0) pins motion.
#define BLOCK_SYNC() do {                                   \
    __builtin_amdgcn_sched_barrier(0);                      \
    asm volatile("s_waitcnt lgkmcnt(0)" ::: "memory");      \
    __builtin_amdgcn_s_barrier();                           \
    __builtin_amdgcn_sched_barrier(0);                      \
} while (0)

// ---------------------------------------------------------------------------
// Merged prep: blocks [0,576) transpose x -> x_t bf16 (XCD-aligned tiles);
// blocks [576,1296) convert weights to bf16 (q reordered to kc*128+c).
// ---------------------------------------------------------------------------
__global__ __launch_bounds__(256) void pre_kernel(
    const float* __restrict__ x, const float* __restrict__ w,
    const float* __restrict__ wom, unsigned short* __restrict__ xt,
    unsigned short* __restrict__ wbf, unsigned short* __restrict__ womb)
{
    __shared__ float tile[64][130];
    const int t = threadIdx.x;
    const int f = blockIdx.x;

    if (f < 576) {
        const int g  = (f & 7) * 72 + (f >> 3);      // bijective [0,576)
        const int b  = g / 144;
        const int p0 = (g - b * 144) * 64;
#pragma unroll
        for (int j = 0; j < 8; j++) {               // read: 4 px per thread (float4)
            const int i  = j * 256 + t;
            const int c  = i >> 4;
            const int p4 = (i & 15) * 4;
            const float4 v = *(const float4*)(x + ((size_t)(b * CIN_ + c) * HW + p0 + p4));
            tile[p4 + 0][c] = v.x; tile[p4 + 1][c] = v.y;
            tile[p4 + 2][c] = v.z; tile[p4 + 3][c] = v.w;
        }
        __syncthreads();
#pragma unroll
        for (int j = 0; j < 8; j++) {               // write: 4 c per thread (8 B bf16)
            const int i   = j * 256 + t;
            const int pxl = i >> 5;
            const int c4  = (i & 31) * 4;
            uint2 v;
            v.x = pkbf(tile[pxl][c4 + 1], tile[pxl][c4 + 0]);
            v.y = pkbf(tile[pxl][c4 + 3], tile[pxl][c4 + 2]);
            *(uint2*)(xt + ((size_t)(b * HW + p0 + pxl) * CIN_ + c4)) = v;
        }
    } else {
        const int i = (f - 576) * 256 + t;
        if (i < COUT_ * 1152) {
            const int oc = i / 1152, r = i - oc * 1152;
            const int kc = r >> 7, c = r & 127;
            wbf[i] = f2bf(w[(size_t)oc * 1152 + c * 9 + kc]);
        } else {
            const int i2 = i - COUT_ * 1152;
            if (i2 < 32 * 1152) {
                const int row = i2 / 1152, r = i2 - row * 1152;
                const int kc = r >> 7, c = r & 127;
                womb[i2] = (row < 27) ? f2bf(wom[(size_t)row * 1152 + c * 9 + kc]) : 0;
            }
        }
    }
}

// ---------------------------------------------------------------------------
// Fused conv kernel.  Grid 768 (XCD-aligned), 512 thr, 48 px / block.
//   phase 0a: ALL 8 waves stage the 3x50 zero-padded xt halo of this strip
//             into LDS (150 rows x 256B = 38400B, XOR-swizzled chunks) with
//             2400 coalesced 16B loads — one latency exposure, full MLP.
//   phase 0b: waves 0..5 compute om = womb @ halo (B-frags via ds_read_b128,
//             conflict-free; no border branches — OOB rows are zero).
//             Results -> registers; after a barrier -> som (LDS) + off_out.
//   phase 1:  432 threads build sprep (bilinear corners + mask*weights).
//   phase 2:  per kc {pipelined register gather -> swizzled btile[kc&1],
//             BLOCK_SYNC, MFMA} — unchanged from round 6 (proven).
// LDS: one 38400B pool.  Staging uses all of it; som (5184B @+3456) is
// written only after staging reads complete; sprep (13824B @0) after som;
// btile0/1 (@+3456/+6528) after sprep — each alias sequenced by a barrier.
// ---------------------------------------------------------------------------
__global__ __launch_bounds__(512, 6) void dconv_fused(
    const unsigned short* __restrict__ xt, const unsigned short* __restrict__ wbf,
    const unsigned short* __restrict__ womb, const float* __restrict__ bias,
    float* __restrict__ out, float* __restrict__ off_out)
{
    __shared__ int smem[9600];            // 38400 B
    int*   sprep  = smem;                 // [432*8]
    int*   btile0 = smem + 3456;          // [48*64]
    int*   btile1 = smem + 6528;          // [48*64]
    float* som    = (float*)btile0;       // [27][48] (alias)

    const int t    = threadIdx.x;
    const int wave = __builtin_amdgcn_readfirstlane(t >> 6);
    const int lane = t & 63;
    const int quad = lane >> 4;
    const int m    = lane & 15;
    const int l32  = lane & 31;
    const int half = lane >> 5;

    const int f  = blockIdx.x;
    const int c  = (f & 7) * 96 + (f >> 3);          // bijective [0,768)
    const int b  = c / 192;
    const int p0 = (c - b * 192) * TPX;

    const unsigned short* xtb = xt + (size_t)b * HW * CIN_;

    const int hrow = p0 / 96;             // strip row (48-px strips: single row)
    const int w0   = p0 - hrow * 96;      // 0 or 48

    // ---- phase 0a: stage 3x50 zero-padded halo into LDS -------------------
    // row = r*50+cc  ->  image (y,xx) = (hrow-1+r, w0-1+cc); 16 chunks/row,
    // chunk ch stored at ch^(row&7) (2-way-free on both write and read).
#pragma unroll
    for (int k = 0; k < 5; k++) {
        const int i = k * 512 + t;
        if (i < 2400) {
            const int row = i >> 4;
            const int ch  = i & 15;
            const int r   = row / 50;
            const int cc  = row - r * 50;
            const int y   = hrow + r - 1;
            const int xx  = w0 + cc - 1;
            uint4 v = make_uint4(0u, 0u, 0u, 0u);
            if (((unsigned)y < 96u) && ((unsigned)xx < 96u))
                v = *(const uint4*)(xtb + (size_t)(y * 96 + xx) * CIN_ + ch * 8);
            *(uint4*)&smem[row * 64 + ((ch ^ (row & 7)) << 2)] = v;
        }
    }
    __syncthreads();

    // ---- phase 0b: offset/mask conv, B-frags from LDS ---------------------
    float4v acc2;
#pragma unroll
    for (int r = 0; r < 4; r++) acc2[r] = 0.f;

    if (wave < 6) {
        const int pxg = wave >> 1;
        const int mt  = wave & 1;
        const int pgl = pxg * 16 + m;

#pragma unroll
        for (int kc = 0; kc < 9; kc++) {
            const int ki = kc / 3, kj = kc - 3 * (kc / 3);
            const int sr = ki * 50 + pgl + kj;            // staged row 0..149
            const short* brow = (const short*)smem + sr * 128;
            const short* abase = (const short*)womb + (size_t)(mt * 16 + m) * 1152 + kc * 128;
#pragma unroll
            for (int kst = 0; kst < 4; kst++) {
                const int c16s = (kst * 4 + quad) ^ (sr & 7);
                const short8v bfv = *(const short8v*)(brow + c16s * 8);
                const short8v av  = *(const short8v*)(abase + kst * 32 + quad * 8);
                acc2 = __builtin_amdgcn_mfma_f32_16x16x32_bf16(av, bfv, acc2, 0, 0, 0);
            }
        }
    }
    __syncthreads();                      // staging reads done before som write

    if (wave < 6) {
        const int pxg = wave >> 1;
        const int mt  = wave & 1;
        const int pgl = pxg * 16 + m;
        const int pg  = p0 + pgl;
#pragma unroll
        for (int r = 0; r < 4; r++) {
            const int oc = mt * 16 + quad * 4 + r;
            if (oc < 27) som[oc * TPX + pgl] = acc2[r];
            if (oc < 18) off_out[(size_t)(b * 18 + oc) * HW + pg] = acc2[r];
        }
    }
    __syncthreads();

    // ---- phase 1: sampling prep (reads som, writes sprep; disjoint) -------
    if (t < 432) {
        const int kc  = t / 48;
        const int pxl = t - kc * 48;
        const int pg  = p0 + pxl;
        const int h   = pg / 96;
        const int w   = pg - h * 96;
        const int ki  = kc / 3, kj = kc - 3 * (kc / 3);

        const float o1 = som[kc * TPX + pxl];
        const float o2 = som[(9 + kc) * TPX + pxl];
        const float mr = som[(18 + kc) * TPX + pxl];
        const float mk = 2.f / (1.f + __expf(-mr));   // sigmoid * MASK_SCALE

        const float py = (float)(h - 1 + ki) + o1;
        const float px = (float)(w - 1 + kj) + o2;
        const float y0f = floorf(py), x0f = floorf(px);
        const float ly = py - y0f,    lx = px - x0f;
        const int y0 = (int)y0f, x0 = (int)x0f;
        const int y1 = y0 + 1,   x1 = x0 + 1;

        const float w00 = (1.f - ly) * (1.f - lx), w01 = (1.f - ly) * lx;
        const float w10 = ly * (1.f - lx),         w11 = ly * lx;

        const int yc0 = min(max(y0, 0), HH - 1), yc1 = min(max(y1, 0), HH - 1);
        const int xc0 = min(max(x0, 0), WW - 1), xc1 = min(max(x1, 0), WW - 1);
        const bool vy0 = (y0 >= 0) && (y0 < HH), vy1 = (y1 >= 0) && (y1 < HH);
        const bool vx0 = (x0 >= 0) && (x0 < WW), vx1 = (x1 >= 0) && (x1 < WW);

        sprep[t * 8 + 0] = yc0 * 96 + xc0;
        sprep[t * 8 + 1] = yc0 * 96 + xc1;
        sprep[t * 8 + 2] = yc1 * 96 + xc0;
        sprep[t * 8 + 3] = yc1 * 96 + xc1;
        sprep[t * 8 + 4] = __builtin_bit_cast(int, (vy0 && vx0) ? mk * w00 : 0.f);
        sprep[t * 8 + 5] = __builtin_bit_cast(int, (vy0 && vx1) ? mk * w01 : 0.f);
        sprep[t * 8 + 6] = __builtin_bit_cast(int, (vy1 && vx0) ? mk * w10 : 0.f);
        sprep[t * 8 + 7] = __builtin_bit_cast(int, (vy1 && vx1) ? mk * w11 : 0.f);
    }
    __syncthreads();

    // ---- phase 2: pipelined gather + main GEMM (unchanged, proven) --------
    uint2 gbuf[3][4];

#define ISSUE(SL, KCV, ITV) do {                                              \
    const int pxl_ = wave * 6 + (ITV) * 2 + half;                             \
    const int4 id4_ = *(const int4*)&sprep[((KCV) * 48 + pxl_) * 8];          \
    const unsigned co_ = (unsigned)l32 << 3;                                  \
    gbuf[SL][0] = *(const uint2*)((const char*)xtb + (((unsigned)id4_.x << 8) | co_)); \
    gbuf[SL][1] = *(const uint2*)((const char*)xtb + (((unsigned)id4_.y << 8) | co_)); \
    gbuf[SL][2] = *(const uint2*)((const char*)xtb + (((unsigned)id4_.z << 8) | co_)); \
    gbuf[SL][3] = *(const uint2*)((const char*)xtb + (((unsigned)id4_.w << 8) | co_)); \
} while (0)

#define COMBINE(SL, IV) do {                                                  \
    const int pxl_ = wave * 6 + (IV) * 2 + half;                              \
    const float4 w4_ = *(const float4*)&sprep[(kc * 48 + pxl_) * 8 + 4];      \
    const uint2 u0 = gbuf[SL][0], u1 = gbuf[SL][1];                           \
    const uint2 u2 = gbuf[SL][2], u3 = gbuf[SL][3];                           \
    const float v0 = w4_.x*bflo(u0.x) + w4_.y*bflo(u1.x) + w4_.z*bflo(u2.x) + w4_.w*bflo(u3.x); \
    const float v1 = w4_.x*bfhi(u0.x) + w4_.y*bfhi(u1.x) + w4_.z*bfhi(u2.x) + w4_.w*bfhi(u3.x); \
    const float v2 = w4_.x*bflo(u0.y) + w4_.y*bflo(u1.y) + w4_.z*bflo(u2.y) + w4_.w*bflo(u3.y); \
    const float v3 = w4_.x*bfhi(u0.y) + w4_.y*bfhi(u1.y) + w4_.z*bfhi(u2.y) + w4_.w*bfhi(u3.y); \
    uint2 o_;                                                                 \
    o_.x = pkbf(v1, v0);                                                      \
    o_.y = pkbf(v3, v2);                                                      \
    *(uint2*)&bt[pxl_ * 64 + (((l32 >> 1) ^ (pxl_ & 7)) << 2) + ((l32 & 1) << 1)] = o_; \
} while (0)

    float4v acc[3];
#pragma unroll
    for (int j = 0; j < 3; j++)
#pragma unroll
        for (int r = 0; r < 4; r++) acc[j][r] = 0.f;

    // prologue: all three iter-loads of kc=0 in flight
    ISSUE(0, 0, 0);
    ISSUE(1, 0, 1);
    ISSUE(2, 0, 2);

    for (int kc = 0; kc < 9; kc++) {
        int* bt = (kc & 1) ? btile1 : btile0;

        // A-fragments for this kc — issued at phase top, used after barrier
        const short* abase = (const short*)wbf + (size_t)(wave * 16 + m) * 1152 + kc * 128 + quad * 8;
        short8v af[4];
#pragma unroll
        for (int kst = 0; kst < 4; kst++)
            af[kst] = *(const short8v*)(abase + kst * 32);

        // consume slot, immediately reissue it one phase ahead
        COMBINE(0, 0);
        if (kc < 8) ISSUE(0, kc + 1, 0);
        COMBINE(1, 1);
        if (kc < 8) ISSUE(1, kc + 1, 1);
        COMBINE(2, 2);
        if (kc < 8) ISSUE(2, kc + 1, 2);

        BLOCK_SYNC();   // drains LDS writes only; gather/af loads stay in flight

        // MFMA: wave = 16-oc slice; 4 kst x 3 nt; swizzle-matched reads
#pragma unroll
        for (int kst = 0; kst < 4; kst++) {
#pragma unroll
            for (int nt = 0; nt < 3; nt++) {
                const int pxl = nt * 16 + m;
                const short8v bfv = *(const short8v*)((const short*)bt
                    + 2 * (pxl * 64 + (((kst * 4 + quad) ^ (m & 7)) << 2)));
                acc[nt] = __builtin_amdgcn_mfma_f32_16x16x32_bf16(af[kst], bfv, acc[nt], 0, 0, 0);
            }
        }
        // no trailing barrier: next kc writes the other buffer; this kc's
        // ds_reads drain at the next BLOCK_SYNC's lgkmcnt(0).
    }
#undef ISSUE
#undef COMBINE

    // ---- epilogue ---------------------------------------------------------
#pragma unroll
    for (int r = 0; r < 4; r++) {
        const int oc = wave * 16 + quad * 4 + r;
        const float bv = bias[oc];
#pragma unroll
        for (int nt = 0; nt < 3; nt++)
            out[(size_t)(b * COUT_ + oc) * HW + p0 + nt * 16 + m] = acc[nt][r] + bv;
    }
}

extern "C" void kernel_launch(void* const* d_in, const int* in_sizes, int n_in,
                              void* d_out, int out_size, void* d_ws, size_t ws_size,
                              hipStream_t stream) {
    const float* x      = (const float*)d_in[0];
    const float* weight = (const float*)d_in[1];
    const float* bias   = (const float*)d_in[2];
    const float* wom    = (const float*)d_in[3];

    float* out     = (float*)d_out;
    float* off_out = out + OUT_ELEMS;

    unsigned short* xtb  = (unsigned short*)((char*)d_ws + XT_OFF);
    unsigned short* wbf  = (unsigned short*)((char*)d_ws + WBF_OFF);
    unsigned short* womb = (unsigned short*)((char*)d_ws + WOMB_OFF);

    pre_kernel <<<dim3(1296), 256, 0, stream>>>(x, weight, wom, xtb, wbf, womb);
    dconv_fused<<<dim3(768),  512, 0, stream>>>(xtb, wbf, womb, bias, out, off_out);
}